// Round 8
// baseline (780.986 us; speedup 1.0000x reference)
//
#include <hip/hip_runtime.h>

// ---------------------------------------------------------------------------
// 2-layer LSTM (H=51) + Linear(51,1), B=1024, T=1024, fp32.
// R21 = R20 + read hoisting + split g2 accumulators.
//   Post-mortem R20: posu changed the WRITE bank pattern but the conflict
//   counter stayed EXACTLY 1.757e7 -> conflicts come from b128 READS
//   (R16->R17 scaling confirms: reads halved, conflicts halved). Write fix
//   was aimed at the wrong source. vmcnt-drain removal: also 0. Three nulls
//   (VALU cut, conflict/write fix, vmcnt) -> step pinned by a latency chain
//   none of them touch: B2 reads issued ~250cy into the step (inside the L2
//   block, after g1+cell1), exposing ~150cy latency on the serial tail
//   B2-read -> 4-deep g2 MFMA chain -> cell2 -> h2 write -> barrier.
//   - All 4 B-reads hoisted to step top: B2 latency hides under g1/cell1.
//   - g2 split into 2 independent 2-deep chains (g2a=bb2+Ai*B1, g2b=Ah*B2,
//     4 adds at cell entry): MFMA dep depth 4 -> 2. (~1ulp fp32 reorder.)
//   - Last iterations peeled -> steady kn_ unclamped (no cmp/cndmask).
//   - Kept from R20: posu store spread (harmless), lgkm-only raw barrier,
//     14 waves (13 tile + 1 y) waves_per_eu(4,4), fp16 single-term MFMA,
//     fused-rcp cells, exp2-domain gates, bias+Wx in acc init, unroll x2,
//     KPAD=88 b128 reads, ONE barrier/step, L2 one step behind L1,
//     ping-pong buffers, deferred y(k-2) on wave 13, peeled k=0/1.
// ---------------------------------------------------------------------------

#define H     51
#define NROW  204      // 4*H
#define TLEN  1024
#define BPB   16       // batches per block (= mfma N)
#define NTHR  896      // 14 waves
#define NBLK  64
#define KPAD  88       // fp16 row stride (176B)

#define LOG2E  1.442695041f
#define LOG2E2 2.885390082f

typedef __attribute__((ext_vector_type(8))) _Float16 half8;  // 8 f16 = 4 VGPRs
typedef __attribute__((ext_vector_type(4))) float f4;

__device__ __forceinline__ float frcp(float x) { return __builtin_amdgcn_rcpf(x); }
#if __has_builtin(__builtin_amdgcn_exp2f)
__device__ __forceinline__ float ex2(float x) { return __builtin_amdgcn_exp2f(x); }
#else
__device__ __forceinline__ float ex2(float x) { return __expf(x * 0.6931471806f); }
#endif

// k-layout permutation within each 8-group (kept from R20; harmless).
__device__ __forceinline__ int posu(int u) {
    return (u & ~7) | ((u & 3) << 1) | ((u >> 2) & 1);
}
__device__ __forceinline__ int ipos(int p) {   // inverse of posu
    return (p & ~7) | ((p & 1) << 2) | ((p >> 1) & 3);
}

__device__ __forceinline__ half8 lds8h(const _Float16* p) {  // one ds_read_b128
    return *(const half8*)__builtin_assume_aligned(p, 16);
}

// LDS-only barrier: no vmcnt drain (xnext global load stays in flight).
__device__ __forceinline__ void block_sync_lds() {
    asm volatile("s_waitcnt lgkmcnt(0)\n\ts_barrier" ::: "memory");
}

#define MFMA(ACC, A, B) \
    ACC = __builtin_amdgcn_mfma_f32_16x16x32_f16((A), (B), (ACC), 0, 0, 0)

// A-frag for 16x16x32: lane holds A[m=lane&15][k=quad*8+j], j=0..7.
// Source W is [204][51] row-major, PyTorch rows g*51+u; permuted row
// prow = 4u+g -> src row = (prow&3)*51 + (prow>>2). Column for register j is
// the unit stored at LDS position kt*32+q*8+j, i.e. ipos(...). Zero-pad
// prow>=204 and unit>=51. Rows pre-scaled by log2e (2log2e for gate g).
__device__ __forceinline__ half8 load_wfrag(const float* __restrict__ W,
                                            int tile, int kt, int q, int mcol)
{
    half8 hf;
    const int prow = tile * 16 + mcol;
    const float sc = ((prow & 3) == 2) ? LOG2E2 : LOG2E;
#pragma unroll
    for (int j = 0; j < 8; ++j) {
        const int kk = ipos(kt * 32 + q * 8 + j);    // permuted k layout
        float v = 0.0f;
        if (prow < NROW && kk < H) {
            const int srow = (prow & 3) * H + (prow >> 2);
            v = W[srow * H + kk];
        }
        hf[j] = (_Float16)(v * sc);
    }
    return hf;
}

// Fused LSTM cell (exp2-domain pre-activations), 5 ex2 + 3 rcp:
//   c' = c*rcp(1+e_f) + (Eg-1)*rcp((1+e_i)(Eg+1))
//   h' = (Ec-1)*rcp((Ec+1)(1+e_o))
__device__ __forceinline__ float cell(float a_i, float a_f, float b_g,
                                      float d_o, float* c)
{
    const float e_i = ex2(-a_i);
    const float e_f = ex2(-a_f);
    const float Eg  = ex2(b_g);
    const float f   = frcp(1.0f + e_f);
    const float ig  = (Eg - 1.0f) * frcp((1.0f + e_i) * (Eg + 1.0f));
    const float cn  = fmaf(f, *c, ig);
    *c = cn;
    const float Ec  = ex2(cn * LOG2E2);
    const float e_o = ex2(-d_o);
    return (Ec - 1.0f) * frcp((Ec + 1.0f) * (1.0f + e_o));
}

__global__
__attribute__((amdgpu_flat_work_group_size(NTHR, NTHR), amdgpu_waves_per_eu(4, 4)))
void lstm2_kernel(const float* __restrict__ input,
                  const float* __restrict__ W_ih1, const float* __restrict__ W_hh1,
                  const float* __restrict__ b_ih1, const float* __restrict__ b_hh1,
                  const float* __restrict__ W_ih2, const float* __restrict__ W_hh2,
                  const float* __restrict__ b_ih2, const float* __restrict__ b_hh2,
                  const float* __restrict__ W_lin, const float* __restrict__ b_lin,
                  float* __restrict__ out)
{
    const int tid  = threadIdx.x;
    const int w    = tid >> 6;        // wave 0..13
    const int lane = tid & 63;
    const int q    = lane >> 4;       // quad
    const int mcol = lane & 15;       // batch column (and A-frag m)
    const int b0   = blockIdx.x * BPB;

    const bool tile_wave = (w < 13);
    const bool y_wave    = (w == 13);

    // [buf][plane][mcol][kpos]; planes: 0=h1 1=h2 (fp16, k-permuted layout).
    __shared__ __align__(16) _Float16 hb[2][2][BPB][KPAD];

    {
        _Float16* hz = &hb[0][0][0][0];
        for (int i = tid; i < 2 * 2 * BPB * KPAD; i += NTHR) hz[i] = (_Float16)0.0f;
    }

    // ---- persistent weight fragments: wave w owns tile w ------------------
    half8 A1[2], Ai[2], Ah[2];            // W_hh1 / W_ih2 / W_hh2, x Ktile
    f4 bb1, bb2, wxv;
    float c1 = 0.0f, c2 = 0.0f;
    const int t = w;                      // tile
    const int u = 4 * t + q;              // this lane's unit (<= 51 for t<13)
    const int wpos = posu(u);             // permuted store position

    if (tile_wave) {
#pragma unroll
        for (int kt = 0; kt < 2; ++kt) {
            A1[kt] = load_wfrag(W_hh1, t, kt, q, mcol);
            Ai[kt] = load_wfrag(W_ih2, t, kt, q, mcol);
            Ah[kt] = load_wfrag(W_hh2, t, kt, q, mcol);
        }
#pragma unroll
        for (int j = 0; j < 4; ++j) {     // gate j of unit u (PyTorch row j*H+u)
            const bool v = (u < H);
            const float sc = (j == 2) ? LOG2E2 : LOG2E;
            bb1[j] = v ? sc * (b_ih1[j * H + u] + b_hh1[j * H + u]) : 0.0f;
            bb2[j] = v ? sc * (b_ih2[j * H + u] + b_hh2[j * H + u]) : 0.0f;
            wxv[j] = v ? sc * W_ih1[j * H + u] : 0.0f;
        }
    }

    float wl[16];                   // wave13: y weights for PERMUTED positions
    if (y_wave) {
#pragma unroll
        for (int i = 0; i < 16; ++i) {
            const int r = ipos(q * 16 + i);
            wl[i] = (r < H) ? W_lin[r] : 0.0f;
        }
    }
    const float blin = b_lin[0];

    float xcur = input[(size_t)(b0 + mcol) * TLEN + 0];

    __syncthreads();                       // zeros visible (full sync once)

// One LSTM step: reads buf RB (h1(k-1), h2(k-2)), writes buf WB.
// RB/WB/L2EN/YEN/CL literals -> guards fold, LDS addresses loop-invariant.
// All B reads issued at step top; g2 split into two 2-deep MFMA chains.
#define STEP(KK, RB, WB, L2EN, YEN, CL)                                        \
do {                                                                           \
    const int k_  = (KK);                                                      \
    const int kn_ = (CL) ? ((k_ + 1 < TLEN) ? (k_ + 1) : (TLEN - 1)) : (k_ + 1); \
    const float xnext_ = input[(size_t)(b0 + mcol) * TLEN + kn_];              \
    if (tile_wave) {                                                           \
        half8 B1a = lds8h(&hb[RB][0][mcol][q * 8]);                            \
        half8 B1b = lds8h(&hb[RB][0][mcol][32 + q * 8]);                       \
        half8 B2a, B2b;                                                        \
        if (L2EN) {                                                            \
            B2a = lds8h(&hb[RB][1][mcol][q * 8]);                              \
            B2b = lds8h(&hb[RB][1][mcol][32 + q * 8]);                         \
        }                                                                      \
        f4 g1;                                                                 \
        g1[0] = fmaf(wxv[0], xcur, bb1[0]);                                    \
        g1[1] = fmaf(wxv[1], xcur, bb1[1]);                                    \
        g1[2] = fmaf(wxv[2], xcur, bb1[2]);                                    \
        g1[3] = fmaf(wxv[3], xcur, bb1[3]);                                    \
        MFMA(g1, A1[0], B1a);  MFMA(g1, A1[1], B1b);                           \
        f4 g2a, g2b;                                                           \
        if (L2EN) {                                                            \
            g2a = bb2;                                                         \
            MFMA(g2a, Ai[0], B1a);  MFMA(g2a, Ai[1], B1b);                     \
            g2b[0] = 0.0f; g2b[1] = 0.0f; g2b[2] = 0.0f; g2b[3] = 0.0f;        \
            MFMA(g2b, Ah[0], B2a);  MFMA(g2b, Ah[1], B2b);                     \
        }                                                                      \
        /* L1 acts (step k) — overlaps g2 MFMA latency */                      \
        const float h1n = cell(g1[0], g1[1], g1[2], g1[3], &c1);               \
        hb[WB][0][mcol][wpos] = (_Float16)h1n;                                 \
        if (L2EN) {                                                            \
            /* L2 acts (step k-1) */                                           \
            const float h2n = cell(g2a[0] + g2b[0], g2a[1] + g2b[1],           \
                                   g2a[2] + g2b[2], g2a[3] + g2b[3], &c2);     \
            hb[WB][1][mcol][wpos] = (_Float16)h2n;                             \
        }                                                                      \
    } else if (y_wave && (YEN)) {                                              \
        /* deferred y(k-2) from h2 plane of buf RB (stable this iter) */       \
        half8 y0 = lds8h(&hb[RB][1][mcol][q * 16]);                            \
        half8 y1 = lds8h(&hb[RB][1][mcol][q * 16 + 8]);                        \
        float yp = 0.0f;                                                       \
        _Pragma("unroll")                                                      \
        for (int i = 0; i < 8; ++i) {                                          \
            yp += wl[i]     * (float)y0[i];                                    \
            yp += wl[i + 8] * (float)y1[i];                                    \
        }                                                                      \
        yp += __shfl_xor(yp, 16);                                              \
        yp += __shfl_xor(yp, 32);                                              \
        if (q == 0) out[(size_t)(b0 + mcol) * TLEN + (k_ - 2)] = yp + blin;    \
    }                                                                          \
    block_sync_lds();                                                          \
    xcur = xnext_;                                                             \
} while (0)

    // k even: rb=1, wbuf=0; k odd: rb=0, wbuf=1.
    STEP(0, 1, 0, 0, 0, 0);                // L1 only (h2(-1) stays 0)
    STEP(1, 0, 1, 1, 0, 0);                // +L2 (step 0); y starts at k=2
    for (int k = 2; k < TLEN - 2; k += 2) {  // steady: no guards, no clamp
        STEP(k, 1, 0, 1, 1, 0);
        STEP(k + 1, 0, 1, 1, 1, 0);
    }
    STEP(TLEN - 2, 1, 0, 1, 1, 0);         // kn = TLEN-1, no clamp needed
    STEP(TLEN - 1, 0, 1, 1, 1, 1);         // clamp (kn would be TLEN)
    STEP(TLEN,     1, 0, 1, 1, 1);         // tail: L2(step 1023) + y(1022)
#undef STEP

    // epilogue: y(T-1) from h2 plane of buf (TLEN & 1) = 0 (= wbuf at k=TLEN)
    if (y_wave) {
        half8 y0 = lds8h(&hb[0][1][mcol][q * 16]);
        half8 y1 = lds8h(&hb[0][1][mcol][q * 16 + 8]);
        float yp = 0.0f;
#pragma unroll
        for (int i = 0; i < 8; ++i) {
            yp += wl[i]     * (float)y0[i];
            yp += wl[i + 8] * (float)y1[i];
        }
        yp += __shfl_xor(yp, 16);
        yp += __shfl_xor(yp, 32);
        if (q == 0) out[(size_t)(b0 + mcol) * TLEN + (TLEN - 1)] = yp + blin;
    }
}

extern "C" void kernel_launch(void* const* d_in, const int* in_sizes, int n_in,
                              void* d_out, int out_size, void* d_ws, size_t ws_size,
                              hipStream_t stream)
{
    const float* input = (const float*)d_in[0];
    const float* W_ih1 = (const float*)d_in[1];
    const float* W_hh1 = (const float*)d_in[2];
    const float* b_ih1 = (const float*)d_in[3];
    const float* b_hh1 = (const float*)d_in[4];
    const float* W_ih2 = (const float*)d_in[5];
    const float* W_hh2 = (const float*)d_in[6];
    const float* b_ih2 = (const float*)d_in[7];
    const float* b_hh2 = (const float*)d_in[8];
    const float* W_lin = (const float*)d_in[9];
    const float* b_lin = (const float*)d_in[10];

    float* out = (float*)d_out;

    hipLaunchKernelGGL(lstm2_kernel, dim3(NBLK), dim3(NTHR), 0, stream,
                       input, W_ih1, W_hh1, b_ih1, b_hh1,
                       W_ih2, W_hh2, b_ih2, b_hh2, W_lin, b_lin,
                       out);
}

// Round 9
// 724.155 us; speedup vs baseline: 1.0785x; 1.0785x over previous
//
#include <hip/hip_runtime.h>

// ---------------------------------------------------------------------------
// 2-layer LSTM (H=51) + Linear(51,1), B=1024, T=1024, fp32.
// R22 = layer-split waves + lagged L2 + shadow reads.
//   Post-mortem R17-R21: four nulls; all pipes ~50% -> step = SUM of phases:
//   post-barrier 52-read DS burst (~1000cy incl inherent b128 2-way) with
//   idle VALU, then last wave's ~300cy tail with idle DS. Conflicts are
//   inherent to b128 (minimal 2-way), only read COUNT is reducible.
//   Self-recurrence forces post-barrier reads only for a layer's OWN h;
//   cross-layer h1->L2 is early-readable if L2 lags 2 steps.
//   - waves 0-6: L1, tiles {w,7+w} (t=13 dummy -> computes exact 0).
//     At step k: read h1(k-1) [post-barrier, 2 b128], compute L1(k),
//     write h1(k). 14-read share of the burst.
//   - waves 7-13: L2, tiles {w-7,7+(w-7)}. At step k: compute L2(k-2):
//     h1(k-2) ALREADY IN REGS (shadow-read during step k-1; 2 steps old =
//     stable), read h2(k-3) post-barrier [2 b128], write h2(k-2), then
//     shadow-read h1(k-1) for next step (lands in the DS-idle tail).
//   - y folded into L2 wave 7: its B2 frags ARE h2(k-3) -> lane-local dot
//     (wl indexed by ipos) + shfl reduce. y-wave eliminated.
//   Burst 54 -> 28 reads; total 54 -> 42. Occupancy stays 14 waves
//   (3.5/SIMD) - R19's fat-wave failure was 2/SIMD occupancy, not fatness.
//   - h1 ring 4-deep (slot k&3), h2 ping-pong (slot k&1), unroll x4 for
//     literal slots. Steps k=0..1025 (+1 tail step for the lag), peeled
//     k=0..3 and 1024/1025; epilogue y(1023).
//   - Kept: fp16 single-term MFMA, fused-rcp cells, exp2-domain gates,
//     bias+Wx in acc init, posu/ipos store spread, KPAD=88 b128 reads,
//     lgkm-only raw barrier, ONE barrier/step, waves_per_eu(4,4).
//   All cell math bit-identical to R21 (L2 just runs one step later).
// ---------------------------------------------------------------------------

#define H     51
#define NROW  204      // 4*H
#define TLEN  1024
#define BPB   16       // batches per block (= mfma N)
#define NTHR  896      // 14 waves
#define NBLK  64
#define KPAD  88       // fp16 row stride (176B)

#define LOG2E  1.442695041f
#define LOG2E2 2.885390082f

typedef __attribute__((ext_vector_type(8))) _Float16 half8;  // 8 f16 = 4 VGPRs
typedef __attribute__((ext_vector_type(4))) float f4;

__device__ __forceinline__ float frcp(float x) { return __builtin_amdgcn_rcpf(x); }
#if __has_builtin(__builtin_amdgcn_exp2f)
__device__ __forceinline__ float ex2(float x) { return __builtin_amdgcn_exp2f(x); }
#else
__device__ __forceinline__ float ex2(float x) { return __expf(x * 0.6931471806f); }
#endif

// k-layout permutation within each 8-group (store spread; R20-proven exact).
__device__ __forceinline__ int posu(int u) {
    return (u & ~7) | ((u & 3) << 1) | ((u >> 2) & 1);
}
__device__ __forceinline__ int ipos(int p) {   // inverse of posu
    return (p & ~7) | ((p & 1) << 2) | ((p >> 1) & 3);
}

__device__ __forceinline__ half8 lds8h(const _Float16* p) {  // one ds_read_b128
    return *(const half8*)__builtin_assume_aligned(p, 16);
}

// LDS-only barrier: no vmcnt drain.
__device__ __forceinline__ void block_sync_lds() {
    asm volatile("s_waitcnt lgkmcnt(0)\n\ts_barrier" ::: "memory");
}

#define MFMA(ACC, A, B) \
    ACC = __builtin_amdgcn_mfma_f32_16x16x32_f16((A), (B), (ACC), 0, 0, 0)

// A-frag loader (R20-proven): lane holds A[m=lane&15][k=quad*8+j]; source W
// [204][51] row-major, prow=4u+g permutation, column = ipos(k-position),
// zero-pad prow>=204 / unit>=51; rows pre-scaled by log2e (2log2e gate g).
__device__ __forceinline__ half8 load_wfrag(const float* __restrict__ W,
                                            int tile, int kt, int q, int mcol)
{
    half8 hf;
    const int prow = tile * 16 + mcol;
    const float sc = ((prow & 3) == 2) ? LOG2E2 : LOG2E;
#pragma unroll
    for (int j = 0; j < 8; ++j) {
        const int kk = ipos(kt * 32 + q * 8 + j);    // permuted k layout
        float v = 0.0f;
        if (prow < NROW && kk < H) {
            const int srow = (prow & 3) * H + (prow >> 2);
            v = W[srow * H + kk];
        }
        hf[j] = (_Float16)(v * sc);
    }
    return hf;
}

// Fused LSTM cell (exp2-domain pre-activations), 5 ex2 + 3 rcp (R18-proven).
// All-zero gates (dummy tiles) yield h=0 exactly (c stays 0).
__device__ __forceinline__ float cell(float a_i, float a_f, float b_g,
                                      float d_o, float* c)
{
    const float e_i = ex2(-a_i);
    const float e_f = ex2(-a_f);
    const float Eg  = ex2(b_g);
    const float f   = frcp(1.0f + e_f);
    const float ig  = (Eg - 1.0f) * frcp((1.0f + e_i) * (Eg + 1.0f));
    const float cn  = fmaf(f, *c, ig);
    *c = cn;
    const float Ec  = ex2(cn * LOG2E2);
    const float e_o = ex2(-d_o);
    return (Ec - 1.0f) * frcp((Ec + 1.0f) * (1.0f + e_o));
}

__global__
__attribute__((amdgpu_flat_work_group_size(NTHR, NTHR), amdgpu_waves_per_eu(4, 4)))
void lstm2_kernel(const float* __restrict__ input,
                  const float* __restrict__ W_ih1, const float* __restrict__ W_hh1,
                  const float* __restrict__ b_ih1, const float* __restrict__ b_hh1,
                  const float* __restrict__ W_ih2, const float* __restrict__ W_hh2,
                  const float* __restrict__ b_ih2, const float* __restrict__ b_hh2,
                  const float* __restrict__ W_lin, const float* __restrict__ b_lin,
                  float* __restrict__ out)
{
    const int tid  = threadIdx.x;
    const int w    = tid >> 6;        // wave 0..13
    const int lane = tid & 63;
    const int q    = lane >> 4;       // quad
    const int mcol = lane & 15;       // batch column (and A-frag m)
    const int b0   = blockIdx.x * BPB;

    const bool isL1 = (w < 7);
    const int  tw   = isL1 ? w : (w - 7);

    // h1 ring (4-deep, slot k&3) and h2 ping-pong (slot k&1); fp16,
    // k-permuted (posu) layout. Dummy/pad positions stay harmless.
    __shared__ __align__(16) _Float16 h1r[4][BPB][KPAD];
    __shared__ __align__(16) _Float16 h2r[2][BPB][KPAD];

    {
        _Float16* p1 = &h1r[0][0][0];
        for (int i = tid; i < 4 * BPB * KPAD; i += NTHR) p1[i] = (_Float16)0.0f;
        _Float16* p2 = &h2r[0][0][0];
        for (int i = tid; i < 2 * BPB * KPAD; i += NTHR) p2[i] = (_Float16)0.0f;
    }

    // ---- persistent per-wave state (role-dependent) ------------------------
    // L1: Wa = W_hh1 frags; bbv = bb1; wxv = wx; cc = c1.
    // L2: Wa = W_ih2, Wb = W_hh2; bbv = bb2; cc = c2.
    half8 Wa[2][2], Wb[2][2];
    f4 bbv[2], wxv[2];
    float cc[2] = {0.0f, 0.0f};
    int wp[2];
    const int tt[2] = {tw, 7 + tw};       // t=13 (w==6/13 slot1) = dummy
#pragma unroll
    for (int s = 0; s < 2; ++s) {
        const int t = tt[s];
        const int u = 4 * t + q;
        wp[s] = posu(u);
#pragma unroll
        for (int kt = 0; kt < 2; ++kt) {
            if (isL1) {
                Wa[s][kt] = load_wfrag(W_hh1, t, kt, q, mcol);
            } else {
                Wa[s][kt] = load_wfrag(W_ih2, t, kt, q, mcol);
                Wb[s][kt] = load_wfrag(W_hh2, t, kt, q, mcol);
            }
        }
#pragma unroll
        for (int j = 0; j < 4; ++j) {
            const bool v = (t < 13) && (u < H);
            const float sc = (j == 2) ? LOG2E2 : LOG2E;
            if (isL1) {
                bbv[s][j] = v ? sc * (b_ih1[j * H + u] + b_hh1[j * H + u]) : 0.0f;
                wxv[s][j] = v ? sc * W_ih1[j * H + u] : 0.0f;
            } else {
                bbv[s][j] = v ? sc * (b_ih2[j * H + u] + b_hh2[j * H + u]) : 0.0f;
                wxv[s][j] = 0.0f;
            }
        }
    }

    float wl_a[8], wl_b[8];               // wave 7: y weights per k-position
    if (w == 7) {
#pragma unroll
        for (int j = 0; j < 8; ++j) {
            const int ra = ipos(q * 8 + j);
            const int rb = ipos(32 + q * 8 + j);
            wl_a[j] = (ra < H) ? W_lin[ra] : 0.0f;
            wl_b[j] = (rb < H) ? W_lin[rb] : 0.0f;
        }
    }
    const float blin = b_lin[0];

    float xcur = input[(size_t)(b0 + mcol) * TLEN + 0];   // L1 only
    half8 e1a = {0, 0, 0, 0, 0, 0, 0, 0};                 // shadow h1 frags
    half8 e1b = {0, 0, 0, 0, 0, 0, 0, 0};

    __syncthreads();                       // zeros visible (full sync once)

// One pipeline step k. L1 computes L1(k); L2 computes L2(k-2); y(k-3).
// S1W=k&3, S1R=(k+3)&3, S2W=k&1, S2R=(k+1)&1 -- passed as literals.
// ERE: shadow-read h1(k-1) (slot S1R, same data L1 reads this step) for
// next step's L2. Issued after L2 compute -> lands in the DS-idle tail.
#define STEP(KK, S1W, S1R, S2W, S2R, L1E, L2E, YE, ERE)                        \
do {                                                                           \
    const int k_ = (KK);                                                       \
    if (isL1) {                                                                \
        if (L1E) {                                                             \
            const int kn_ = (k_ + 1 < TLEN) ? (k_ + 1) : (TLEN - 1);           \
            const float xn_ = input[(size_t)(b0 + mcol) * TLEN + kn_];         \
            half8 B1a = lds8h(&h1r[S1R][mcol][q * 8]);                         \
            half8 B1b = lds8h(&h1r[S1R][mcol][32 + q * 8]);                    \
            f4 g0, g1;                                                         \
            g0[0] = fmaf(wxv[0][0], xcur, bbv[0][0]);                          \
            g0[1] = fmaf(wxv[0][1], xcur, bbv[0][1]);                          \
            g0[2] = fmaf(wxv[0][2], xcur, bbv[0][2]);                          \
            g0[3] = fmaf(wxv[0][3], xcur, bbv[0][3]);                          \
            g1[0] = fmaf(wxv[1][0], xcur, bbv[1][0]);                          \
            g1[1] = fmaf(wxv[1][1], xcur, bbv[1][1]);                          \
            g1[2] = fmaf(wxv[1][2], xcur, bbv[1][2]);                          \
            g1[3] = fmaf(wxv[1][3], xcur, bbv[1][3]);                          \
            MFMA(g0, Wa[0][0], B1a);  MFMA(g0, Wa[0][1], B1b);                 \
            MFMA(g1, Wa[1][0], B1a);  MFMA(g1, Wa[1][1], B1b);                 \
            const float h0 = cell(g0[0], g0[1], g0[2], g0[3], &cc[0]);         \
            const float h1v = cell(g1[0], g1[1], g1[2], g1[3], &cc[1]);        \
            h1r[S1W][mcol][wp[0]] = (_Float16)h0;                              \
            h1r[S1W][mcol][wp[1]] = (_Float16)h1v;                             \
            xcur = xn_;                                                        \
        }                                                                      \
    } else {                                                                   \
        if (L2E) {                                                             \
            half8 B2a = lds8h(&h2r[S2R][mcol][q * 8]);                         \
            half8 B2b = lds8h(&h2r[S2R][mcol][32 + q * 8]);                    \
            f4 g0 = bbv[0], g1 = bbv[1];                                       \
            MFMA(g0, Wa[0][0], e1a);  MFMA(g0, Wa[0][1], e1b);  /* ready */    \
            MFMA(g1, Wa[1][0], e1a);  MFMA(g1, Wa[1][1], e1b);                 \
            MFMA(g0, Wb[0][0], B2a);  MFMA(g0, Wb[0][1], B2b);                 \
            MFMA(g1, Wb[1][0], B2a);  MFMA(g1, Wb[1][1], B2b);                 \
            if (ERE) {      /* shadow-read h1(k-1) for next step's L2 */       \
                e1a = lds8h(&h1r[S1R][mcol][q * 8]);                           \
                e1b = lds8h(&h1r[S1R][mcol][32 + q * 8]);                      \
            }                                                                  \
            const float h0 = cell(g0[0], g0[1], g0[2], g0[3], &cc[0]);         \
            const float h1v = cell(g1[0], g1[1], g1[2], g1[3], &cc[1]);        \
            h2r[S2W][mcol][wp[0]] = (_Float16)h0;                              \
            h2r[S2W][mcol][wp[1]] = (_Float16)h1v;                             \
            if ((YE) && w == 7) {   /* y(k-3) from B2 = h2(k-3), free reads */ \
                float yp = 0.0f;                                               \
                _Pragma("unroll")                                              \
                for (int j = 0; j < 8; ++j) {                                  \
                    yp += wl_a[j] * (float)B2a[j];                             \
                    yp += wl_b[j] * (float)B2b[j];                             \
                }                                                              \
                yp += __shfl_xor(yp, 16);                                      \
                yp += __shfl_xor(yp, 32);                                      \
                if (q == 0) out[(size_t)(b0 + mcol) * TLEN + (k_ - 3)] = yp + blin; \
            }                                                                  \
        } else if (ERE) {                                                      \
            e1a = lds8h(&h1r[S1R][mcol][q * 8]);                               \
            e1b = lds8h(&h1r[S1R][mcol][32 + q * 8]);                          \
        }                                                                      \
    }                                                                          \
    block_sync_lds();                                                          \
} while (0)

    // Pipeline: L1 at steps 0..1023; L2(k-2) at steps 2..1025; y(k-3) at 3..1025.
    STEP(0, 0, 3, 0, 1, 1, 0, 0, 0);
    STEP(1, 1, 0, 1, 0, 1, 0, 0, 1);       // shadow-read h1(0)
    STEP(2, 2, 1, 0, 1, 1, 1, 0, 1);       // L2(0): e1=h1(0), h2(-1)=0
    STEP(3, 3, 2, 1, 0, 1, 1, 1, 1);       // + y(0)
    for (int k = 4; k <= 1020; k += 4) {   // steady: k+0..k+3 -> 4..1023
        STEP(k + 0, 0, 3, 0, 1, 1, 1, 1, 1);
        STEP(k + 1, 1, 0, 1, 0, 1, 1, 1, 1);
        STEP(k + 2, 2, 1, 0, 1, 1, 1, 1, 1);
        STEP(k + 3, 3, 2, 1, 0, 1, 1, 1, 1);
    }
    STEP(1024, 0, 3, 0, 1, 0, 1, 1, 1);    // L2(1022), y(1021), shadow h1(1023)
    STEP(1025, 1, 0, 1, 0, 0, 1, 1, 0);    // L2(1023), y(1022)
#undef STEP

    // epilogue: y(1023) from h2(1023) = h2r slot 1 (written at step 1025)
    if (w == 7) {
        half8 ya = lds8h(&h2r[1][mcol][q * 8]);
        half8 yb = lds8h(&h2r[1][mcol][32 + q * 8]);
        float yp = 0.0f;
#pragma unroll
        for (int j = 0; j < 8; ++j) {
            yp += wl_a[j] * (float)ya[j];
            yp += wl_b[j] * (float)yb[j];
        }
        yp += __shfl_xor(yp, 16);
        yp += __shfl_xor(yp, 32);
        if (q == 0) out[(size_t)(b0 + mcol) * TLEN + (TLEN - 1)] = yp + blin;
    }
}

extern "C" void kernel_launch(void* const* d_in, const int* in_sizes, int n_in,
                              void* d_out, int out_size, void* d_ws, size_t ws_size,
                              hipStream_t stream)
{
    const float* input = (const float*)d_in[0];
    const float* W_ih1 = (const float*)d_in[1];
    const float* W_hh1 = (const float*)d_in[2];
    const float* b_ih1 = (const float*)d_in[3];
    const float* b_hh1 = (const float*)d_in[4];
    const float* W_ih2 = (const float*)d_in[5];
    const float* W_hh2 = (const float*)d_in[6];
    const float* b_ih2 = (const float*)d_in[7];
    const float* b_hh2 = (const float*)d_in[8];
    const float* W_lin = (const float*)d_in[9];
    const float* b_lin = (const float*)d_in[10];

    float* out = (float*)d_out;

    hipLaunchKernelGGL(lstm2_kernel, dim3(NBLK), dim3(NTHR), 0, stream,
                       input, W_ih1, W_hh1, b_ih1, b_hh1,
                       W_ih2, W_hh2, b_ih2, b_hh2, W_lin, b_lin,
                       out);
}